// Round 7
// baseline (647.476 us; speedup 1.0000x reference)
//
#include <hip/hip_runtime.h>

#define CCH   640
#define RDIM  128
#define NBS   25
#define NBQ   75
#define CKK   5760
#define SF_B  64000
#define NBLK  256
#define NTHR  512
#define NALL  (NBLK * NTHR)   // 131072 threads, 2048 waves

// ---------------- Workspace layout ----------------
// first 64 ints: barrier cells (zeroed via hipMemsetAsync each call)
#define OFF_PG0   64        // [25][640] pooled(sf)
#define OFF_PGA   16064
#define OFF_PGB   32064
#define OFF_AA    48064     // A ping  [9][640] (k-major)
#define OFF_AB    53824     // A pong
#define OFF_BBA   59584     // beta ping [16]
#define OFF_BBB   59600
#define OFF_HC    59616     // [50][128] combined relu'd hidden
#define OFF_SKT   66016     // [2][25][900]  partials, layout [b][uv*100+p]
#define OFF_SKS   111016    // [2] x [9][25][100] partials, layout [uv][b][p]
#define OFF_CKT   156016    // [25][5760]
#define OFF_CKS   300016    // [25][5760]
#define OFF_TKT   444016    // [9][640][100]

__device__ __forceinline__ void gbar(int* cnt, int id) {
    __syncthreads();
    if (threadIdx.x == 0) {
        __threadfence();                       // release my writes (device scope)
        atomicAdd(&cnt[id], 1);
        while (atomicAdd(&cnt[id], 0) < NBLK)  // RMW spin: always coherent
            __builtin_amdgcn_s_sleep(4);
    }
    __syncthreads();
    __threadfence();                           // acquire: invalidate stale cache
}

__global__ __launch_bounds__(NTHR) void uber(
        const float* __restrict__ sf, const float* __restrict__ qf,
        const float* __restrict__ Wc0, const float* __restrict__ bc0,
        const float* __restrict__ Wc1, const float* __restrict__ bc1,
        const float* __restrict__ Wc2, const float* __restrict__ bc2,
        const float* __restrict__ Wc3, const float* __restrict__ bc3,
        const float* __restrict__ W1,  const float* __restrict__ b1,
        const float* __restrict__ W2,  const float* __restrict__ b2,
        const float* __restrict__ Ws,  const float* __restrict__ bs,
        float* __restrict__ out, float* ws) {
    __shared__ float red[NTHR];
    int* bar = (int*)ws;
    float* Pg0 = ws + OFF_PG0;
    float* PgA = ws + OFF_PGA;
    float* PgB = ws + OFF_PGB;
    float* Aa  = ws + OFF_AA;
    float* Ab  = ws + OFF_AB;
    float* Ba  = ws + OFF_BBA;
    float* Bb  = ws + OFF_BBB;
    float* Hc  = ws + OFF_HC;
    float* SKT = ws + OFF_SKT;
    float* SKS = ws + OFF_SKS;
    float* CKT = ws + OFF_CKT;
    float* CKS = ws + OFF_CKS;
    float* TKT = ws + OFF_TKT;

    int blk = blockIdx.x, t = threadIdx.x;
    int wv = t >> 6, lane = t & 63;
    int gtid = blk * NTHR + t;

    // ---- Phase 0: pool ----
    if (gtid < NBS * CCH) {
        int b = gtid / CCH, c = gtid % CCH;
        const float4* s4 = (const float4*)(sf + b * SF_B + c * 100);
        float acc = 0.f;
#pragma unroll
        for (int q = 0; q < 25; ++q) {
            float4 v = s4[q];
            acc += (v.x + v.y) + (v.z + v.w);
        }
        Pg0[gtid] = acc * 0.01f;
    }
    gbar(bar, 0);

    // ---- Phases 1-4: chain ----
    {
        const float* Wcf[4] = {Wc0, Wc1, Wc2, Wc3};
        const float* bcf[4] = {bc0, bc1, bc2, bc3};
        float* Pbuf[5] = {Pg0, PgA, PgB, PgA, PgB};
        float* Abuf[5] = {(float*)Ws, Aa, Ab, Aa, Ab};
        float* Bbuf[5] = {(float*)bs, Ba, Bb, Ba, Bb};
        for (int s = 0; s < 4; ++s) {
            const float* Wp = Wcf[s];
            const float* bp = bcf[s];
            const float* Wa = Wcf[3 - s];
            const float* ba = bcf[3 - s];
            const float* Pin = Pbuf[s];  float* Pout = Pbuf[s + 1];
            const float* Ain = Abuf[s];  float* Aout = Abuf[s + 1];
            const float* Bin = Bbuf[s];  float* Bout = Bbuf[s + 1];
            if (blk < 90) {
                // A' = A*Wa : block per (k, ctile); 8-way o-split + LDS reduce
                int k = blk / 10, ctile = blk % 10;
                int c = ctile * 64 + lane;
                const float* arow = Ain + k * CCH;
                int o0 = wv * 80;
                float acc = 0.f;
#pragma unroll 8
                for (int o = o0; o < o0 + 80; ++o)
                    acc += arow[o] * Wa[o * CCH + c];
                red[t] = acc;
                __syncthreads();
                if (t < 64) {
                    float sa = 0.f;
#pragma unroll
                    for (int g = 0; g < 8; ++g) sa += red[g * 64 + t];
                    Aout[k * CCH + ctile * 64 + t] = sa;
                }
            } else if (blk < 99) {
                // beta' = beta + A*ba : block per k
                int k = blk - 90;
                const float* arow = Ain + k * CCH;
                float v = arow[t] * ba[t];
                if (t < CCH - NTHR) v += arow[t + NTHR] * ba[t + NTHR];
                red[t] = v;
                __syncthreads();
                if (t < 64) {
                    float sa = 0.f;
#pragma unroll
                    for (int g = 0; g < 8; ++g) sa += red[g * 64 + t];
#pragma unroll
                    for (int m = 32; m >= 1; m >>= 1) sa += __shfl_xor(sa, m);
                    if (t == 0) Bout[k] = sa + Bin[k];
                }
            } else {
                // P' = Wp*P + bp : wave per output
                int gw = (blk - 99) * 8 + wv;          // 0..1255
                for (int job = gw; job < NBS * CCH; job += 157 * 8) {
                    int o = job / NBS, b = job % NBS;
                    const float* wrow = Wp + o * CCH;
                    const float* prow = Pin + b * CCH;
                    float acc = 0.f;
#pragma unroll
                    for (int s5 = 0; s5 < 10; ++s5)
                        acc += wrow[s5 * 64 + lane] * prow[s5 * 64 + lane];
#pragma unroll
                    for (int m = 32; m >= 1; m >>= 1) acc += __shfl_xor(acc, m);
                    if (lane == 0) Pout[b * CCH + o] = acc + bp[o];
                }
            }
            gbar(bar, 1 + s);
        }
    }
    // final: pooled_t = PgB, A4 = Ab (k-major), beta4 = Bb

    // ---- Phase 5: mlp1 (blocks 0..49) + sk partials (blocks 50..255) ----
    if (blk < 50) {
        int pair = blk;
        int b = pair % NBS;
        const float* prow = (pair < NBS ? PgB : Pg0) + b * CCH;
        int og = t >> 7, r = t & 127;
        int c0 = og * 160;
        float acc = 0.f;
#pragma unroll 8
        for (int c = c0; c < c0 + 160; ++c)
            acc += prow[c] * W1[c * RDIM + r];
        red[t] = acc;
        __syncthreads();
        if (t < RDIM) {
            float h = b1[t] + red[t] + red[RDIM + t] + red[2 * RDIM + t] + red[3 * RDIM + t];
            Hc[pair * RDIM + t] = fmaxf(h, 0.f);
        }
    } else {
        int idx = (blk - 50) * NTHR + t;
        if (idx < 2 * NBS * 900) {
            int half = idx / 22500;
            int rem = idx % 22500;
            int b = rem / 900, r2 = rem % 900;      // flat f = k*100+q
            int k = r2 / 100, q = r2 % 100;
            const float* x = sf + b * SF_B + q;
            const float* a4r = Ab + k * CCH;
            const float* wsr = Ws + k * CCH;
            int c0 = half * 320;
            float a0 = 0.f, a1 = 0.f;
#pragma unroll 16
            for (int c = c0; c < c0 + 320; ++c) {
                float xc = x[c * 100];
                a0 += a4r[c] * xc;
                a1 += wsr[c] * xc;
            }
            if (half == 0) { a0 += Bb[k]; a1 += bs[k]; }
            int p = r2 / 9, uv = r2 % 9;            // view coords
            SKT[half * 22500 + b * 900 + uv * 100 + p] = a0;
            SKS[half * 22500 + uv * 2500 + b * 100 + p] = a1;
        }
    }
    gbar(bar, 5);

    // ---- Phase 6: mlp2 ----
    for (int task = gtid; task < 2 * NBS * CKK; task += NALL) {
        int pair = task / CKK, j = task % CKK;
        int branch = pair / NBS, b = pair % NBS;
        const float* h = Hc + pair * RDIM;
        float acc = b2[j];
#pragma unroll 8
        for (int r = 0; r < RDIM; ++r)
            acc += h[r] * W2[r * CKK + j];
        (branch ? CKS : CKT)[b * CKK + j] = acc;
    }
    gbar(bar, 6);

    // ---- Phase 7: task assembly ----
    for (int idx = gtid; idx < 9 * CCH * 100; idx += NALL) {
        int uv = idx / 64000;
        int rem = idx % 64000;
        int c = rem / 100, p = rem % 100;
        float acc = 0.f;
#pragma unroll
        for (int b = 0; b < NBS; ++b)
            acc += CKT[b * CKK + c * 9 + uv] *
                   (SKT[b * 900 + uv * 100 + p] + SKT[22500 + b * 900 + uv * 100 + p]);
        TKT[idx] = acc * 0.04f;
    }
    gbar(bar, 7);

    // ---- Phase 8: involutions ----
    for (int oidx = gtid; oidx < (NBS + NBQ) * SF_B; oidx += NALL) {
        bool support = oidx < NBS * SF_B;
        int b, c, p;
        const float* x;
        if (support) {
            b = oidx / SF_B; int rem = oidx % SF_B; c = rem / 100; p = rem % 100;
            x = sf + b * SF_B + c * 100;
        } else {
            int qi = oidx - NBS * SF_B;
            b = qi / SF_B; int rem = qi % SF_B; c = rem / 100; p = rem % 100;
            x = qf + b * SF_B + c * 100;
        }
        int i = p / 10, j = p % 10;
        float acc = 0.f;
#pragma unroll
        for (int u = 0; u < 3; ++u) {
            int ii = i + u - 1;
            float mrow = ((unsigned)ii < 10u) ? 1.f : 0.f;
            int ci = min(max(ii, 0), 9);
#pragma unroll
            for (int v = 0; v < 3; ++v) {
                int jj = j + v - 1;
                float m = ((unsigned)jj < 10u) ? mrow : 0.f;
                int cj = min(max(jj, 0), 9);
                float xv = x[ci * 10 + cj] * m;
                int uv = u * 3 + v;
                float w = TKT[uv * 64000 + c * 100 + p];
                if (support)
                    w *= CKS[b * CKK + c * 9 + uv] *
                         (SKS[uv * 2500 + b * 100 + p] + SKS[22500 + uv * 2500 + b * 100 + p]);
                acc += w * xv;
            }
        }
        out[oidx] = acc;
    }
}

extern "C" void kernel_launch(void* const* d_in, const int* in_sizes, int n_in,
                              void* d_out, int out_size, void* d_ws, size_t ws_size,
                              hipStream_t stream) {
    const float* sf  = (const float*)d_in[0];
    const float* qf  = (const float*)d_in[1];
    const float* Wc0 = (const float*)d_in[2];
    const float* bc0 = (const float*)d_in[3];
    const float* Wc1 = (const float*)d_in[4];
    const float* bc1 = (const float*)d_in[5];
    const float* Wc2 = (const float*)d_in[6];
    const float* bc2 = (const float*)d_in[7];
    const float* Wc3 = (const float*)d_in[8];
    const float* bc3 = (const float*)d_in[9];
    const float* W1 = (const float*)d_in[10];
    const float* b1 = (const float*)d_in[11];
    const float* W2 = (const float*)d_in[12];
    const float* b2 = (const float*)d_in[13];
    const float* Ws = (const float*)d_in[14];
    const float* bs = (const float*)d_in[15];
    float* out = (float*)d_out;
    float* ws = (float*)d_ws;

    // zero the barrier cells (ws is poisoned 0xAA before every call)
    hipMemsetAsync(d_ws, 0, 64 * sizeof(int), stream);
    uber<<<NBLK, NTHR, 0, stream>>>(sf, qf, Wc0, bc0, Wc1, bc1, Wc2, bc2, Wc3, bc3,
                                    W1, b1, W2, b2, Ws, bs, out, ws);
}

// Round 8
// 639.493 us; speedup vs baseline: 1.0125x; 1.0125x over previous
//
#include <hip/hip_runtime.h>

#define CCH   640
#define RDIM  128
#define NBS   25
#define NBQ   75
#define CKK   5760
#define SF_B  64000
#define NBLK  256
#define NTHR  512
#define NALL  (NBLK * NTHR)   // 131072 threads, 2048 waves

// ---------------- Workspace layout (float offsets) ----------------
// ws[0..63] : int barrier cells (zeroed by tiny memset each call)
#define OFF_PG0   64        // [25][640]
#define OFF_PGA   16064
#define OFF_PGB   32064
#define OFF_AA    48064     // [9][640] ping (k-major)
#define OFF_AB    53824     // pong
#define OFF_BBA   59584     // [16]
#define OFF_BBB   59600
#define OFF_HC    59616     // [50][128]
#define OFF_SKT   66016     // [2][25][900]  layout [half][b][uv*100+p]
#define OFF_SKS   111016    // [2][9][25][100] layout [half][uv][b][p]
#define OFF_CKT   156016    // [25][5760]
#define OFF_CKS   300016
#define OFF_TKT   444016    // [9][640][100]

// Global barrier: arrive = one RMW; poll = plain agent-scope LOAD (no ownership).
__device__ __forceinline__ void gbar(int* cnt, int id) {
    __syncthreads();
    if (threadIdx.x == 0) {
        __threadfence();                       // release block's writes
        atomicAdd(&cnt[id], 1);
        while (__hip_atomic_load(&cnt[id], __ATOMIC_RELAXED,
                                 __HIP_MEMORY_SCOPE_AGENT) < NBLK)
            __builtin_amdgcn_s_sleep(16);
    }
    __syncthreads();
    __threadfence();                           // acquire
}

__global__ __launch_bounds__(NTHR) void uber(
        const float* __restrict__ sf, const float* __restrict__ qf,
        const float* __restrict__ Wc0, const float* __restrict__ bc0,
        const float* __restrict__ Wc1, const float* __restrict__ bc1,
        const float* __restrict__ Wc2, const float* __restrict__ bc2,
        const float* __restrict__ Wc3, const float* __restrict__ bc3,
        const float* __restrict__ W1,  const float* __restrict__ b1,
        const float* __restrict__ W2,  const float* __restrict__ b2,
        const float* __restrict__ Ws,  const float* __restrict__ bs,
        float* __restrict__ out, float* ws) {
    __shared__ float red[NTHR];
    int* bar = (int*)ws;
    float* PG0 = ws + OFF_PG0;
    float* PGA = ws + OFF_PGA;
    float* PGB = ws + OFF_PGB;
    float* AA  = ws + OFF_AA;
    float* AB  = ws + OFF_AB;
    float* BBA = ws + OFF_BBA;
    float* BBB = ws + OFF_BBB;
    float* HC  = ws + OFF_HC;
    float* SKT = ws + OFF_SKT;
    float* SKS = ws + OFF_SKS;
    float* CKT = ws + OFF_CKT;
    float* CKS = ws + OFF_CKS;
    float* TKT = ws + OFF_TKT;

    int blk = blockIdx.x, t = threadIdx.x;
    int wv = t >> 6, lane = t & 63;
    int gtid = blk * NTHR + t;

    // ---- P0: pool (blocks 0..31) + skS 2-way partials (blocks 32..119) ----
    if (blk < 32) {
        int idx = blk * NTHR + t;
        if (idx < NBS * CCH) {
            int b = idx / CCH, c = idx % CCH;
            const float4* s4 = (const float4*)(sf + b * SF_B + c * 100);
            float acc = 0.f;
#pragma unroll
            for (int q = 0; q < 25; ++q) {
                float4 v = s4[q];
                acc += (v.x + v.y) + (v.z + v.w);
            }
            PG0[idx] = acc * 0.01f;
        }
    } else if (blk < 120) {
        int idx = (blk - 32) * NTHR + t;
        if (idx < 2 * NBS * 900) {
            int half = idx / 22500;
            int rem = idx % 22500;
            int b = rem / 900, r2 = rem % 900;    // flat f = k*100+q
            int k = r2 / 100, q = r2 % 100;
            const float* x = sf + b * SF_B + q;
            const float* wsr = Ws + k * CCH;
            int c0 = half * 320;
            float acc = (half == 0) ? bs[k] : 0.f;
#pragma unroll 8
            for (int c = c0; c < c0 + 320; ++c)
                acc += wsr[c] * x[c * 100];
            int p = r2 / 9, uv = r2 % 9;
            SKS[half * 22500 + uv * 2500 + b * 100 + p] = acc;
        }
    }
    gbar(bar, 0);

    // ---- P1..P4: chain steps ----
    {
        const float* Wcf[4] = {Wc0, Wc1, Wc2, Wc3};
        const float* bcf[4] = {bc0, bc1, bc2, bc3};
        const float* Pin_[4] = {PG0, PGA, PGB, PGA};
        float*       Pout_[4] = {PGA, PGB, PGA, PGB};
        const float* Ain_[4] = {Ws, AA, AB, AA};
        float*       Aout_[4] = {AA, AB, AA, AB};
        const float* Bin_[4] = {bs, BBA, BBB, BBA};
        float*       Bout_[4] = {BBA, BBB, BBA, BBB};
        for (int s = 0; s < 4; ++s) {
            const float* Wp = Wcf[s];
            const float* bp = bcf[s];
            const float* Wa = Wcf[3 - s];
            const float* ba = bcf[3 - s];
            const float* Pin = Pin_[s];  float* Pout = Pout_[s];
            const float* Ain = Ain_[s];  float* Aout = Aout_[s];
            const float* Bin = Bin_[s];  float* Bout = Bout_[s];
            if (blk < 90) {
                // A'[k,c] = sum_o A[k,o]*Wa[o,c] : block per (k, ctile64), 8-way o-split
                int k = blk / 10, ctile = blk % 10;
                int c = ctile * 64 + lane;
                const float* arow = Ain + k * CCH;
                int o0 = wv * 80;
                float acc = 0.f;
#pragma unroll 8
                for (int o = o0; o < o0 + 80; ++o)
                    acc += arow[o] * Wa[o * CCH + c];
                red[t] = acc;
                __syncthreads();
                if (t < 64) {
                    float sa = 0.f;
#pragma unroll
                    for (int g = 0; g < 8; ++g) sa += red[g * 64 + t];
                    Aout[k * CCH + ctile * 64 + t] = sa;
                }
            } else if (blk < 99) {
                // beta' = beta + A[k,:] . ba
                int k = blk - 90;
                const float* arow = Ain + k * CCH;
                float v = arow[t] * ba[t];
                if (t < CCH - NTHR) v += arow[t + NTHR] * ba[t + NTHR];
                red[t] = v;
                __syncthreads();
                if (t < 64) {
                    float sa = 0.f;
#pragma unroll
                    for (int g = 0; g < 8; ++g) sa += red[g * 64 + t];
#pragma unroll
                    for (int m = 32; m >= 1; m >>= 1) sa += __shfl_xor(sa, m);
                    if (t == 0) Bout[k] = sa + Bin[k];
                }
            } else {
                // P'[b,o] = Wp[o,:] . P[b,:] + bp[o] : wave per dot
                int gw = (blk - 99) * 8 + wv;          // 0..1255
                for (int job = gw; job < NBS * CCH; job += 157 * 8) {
                    int o = job / NBS, b = job % NBS;
                    const float* wrow = Wp + o * CCH;
                    const float* prow = Pin + b * CCH;
                    float acc = 0.f;
#pragma unroll
                    for (int s5 = 0; s5 < 10; ++s5)
                        acc += wrow[s5 * 64 + lane] * prow[s5 * 64 + lane];
#pragma unroll
                    for (int m = 32; m >= 1; m >>= 1) acc += __shfl_xor(acc, m);
                    if (lane == 0) Pout[b * CCH + o] = acc + bp[o];
                }
            }
            gbar(bar, 1 + s);
        }
    }
    // final: pooled_task = PGB, A4 = AB, beta4 = BBB

    // ---- P5: mlp1 (blocks 0..49) + skT 2-way partials (blocks 50..137) ----
    if (blk < 50) {
        int pair = blk;
        int b = pair % NBS;
        const float* prow = (pair < NBS ? PGB : PG0) + b * CCH;
        int og = t >> 7, r = t & 127;
        int c0 = og * 160;
        float acc = 0.f;
#pragma unroll 8
        for (int c = c0; c < c0 + 160; ++c)
            acc += prow[c] * W1[c * RDIM + r];
        red[t] = acc;
        __syncthreads();
        if (t < RDIM) {
            float h = b1[t] + red[t] + red[RDIM + t] + red[2 * RDIM + t] + red[3 * RDIM + t];
            HC[pair * RDIM + t] = fmaxf(h, 0.f);
        }
    } else if (blk < 138) {
        int idx = (blk - 50) * NTHR + t;
        if (idx < 2 * NBS * 900) {
            int half = idx / 22500;
            int rem = idx % 22500;
            int b = rem / 900, r2 = rem % 900;
            int k = r2 / 100, q = r2 % 100;
            const float* x = sf + b * SF_B + q;
            const float* a4r = AB + k * CCH;
            int c0 = half * 320;
            float acc = (half == 0) ? BBB[k] : 0.f;
#pragma unroll 8
            for (int c = c0; c < c0 + 320; ++c)
                acc += a4r[c] * x[c * 100];
            int p = r2 / 9, uv = r2 % 9;
            SKT[half * 22500 + b * 900 + uv * 100 + p] = acc;
        }
    }
    gbar(bar, 5);

    // ---- P6: mlp2 ----
    for (int job = gtid; job < 2 * NBS * CKK; job += NALL) {
        int pair = job / CKK, j = job % CKK;
        int branch = pair / NBS, b = pair % NBS;
        const float* h = HC + pair * RDIM;
        float acc = b2[j];
#pragma unroll 8
        for (int r = 0; r < RDIM; ++r)
            acc += h[r] * W2[r * CKK + j];
        (branch ? CKS : CKT)[b * CKK + j] = acc;
    }
    gbar(bar, 6);

    // ---- P7: task assembly ----
    for (int idx = gtid; idx < 9 * CCH * 100; idx += NALL) {
        int uv = idx / 64000;
        int rem = idx % 64000;
        int c = rem / 100, p = rem % 100;
        float acc = 0.f;
#pragma unroll
        for (int b = 0; b < NBS; ++b)
            acc += CKT[b * CKK + c * 9 + uv] *
                   (SKT[b * 900 + uv * 100 + p] + SKT[22500 + b * 900 + uv * 100 + p]);
        TKT[idx] = acc * 0.04f;
    }
    gbar(bar, 7);

    // ---- P8: involutions ----
    for (int oidx = gtid; oidx < (NBS + NBQ) * SF_B; oidx += NALL) {
        bool support = oidx < NBS * SF_B;
        int b, c, p;
        const float* x;
        if (support) {
            b = oidx / SF_B; int rem = oidx % SF_B; c = rem / 100; p = rem % 100;
            x = sf + b * SF_B + c * 100;
        } else {
            int qi = oidx - NBS * SF_B;
            b = qi / SF_B; int rem = qi % SF_B; c = rem / 100; p = rem % 100;
            x = qf + b * SF_B + c * 100;
        }
        int i = p / 10, j = p % 10;
        float acc = 0.f;
#pragma unroll
        for (int u = 0; u < 3; ++u) {
            int ii = i + u - 1;
            float mrow = ((unsigned)ii < 10u) ? 1.f : 0.f;
            int ci = min(max(ii, 0), 9);
#pragma unroll
            for (int v = 0; v < 3; ++v) {
                int jj = j + v - 1;
                float m = ((unsigned)jj < 10u) ? mrow : 0.f;
                int cj = min(max(jj, 0), 9);
                float xv = x[ci * 10 + cj] * m;
                int uv = u * 3 + v;
                float w = TKT[uv * 64000 + c * 100 + p];
                if (support)
                    w *= CKS[b * CKK + c * 9 + uv] *
                         (SKS[uv * 2500 + b * 100 + p] + SKS[22500 + uv * 2500 + b * 100 + p]);
                acc += w * xv;
            }
        }
        out[oidx] = acc;
    }
}

extern "C" void kernel_launch(void* const* d_in, const int* in_sizes, int n_in,
                              void* d_out, int out_size, void* d_ws, size_t ws_size,
                              hipStream_t stream) {
    const float* sf  = (const float*)d_in[0];
    const float* qf  = (const float*)d_in[1];
    const float* Wc0 = (const float*)d_in[2];
    const float* bc0 = (const float*)d_in[3];
    const float* Wc1 = (const float*)d_in[4];
    const float* bc1 = (const float*)d_in[5];
    const float* Wc2 = (const float*)d_in[6];
    const float* bc2 = (const float*)d_in[7];
    const float* Wc3 = (const float*)d_in[8];
    const float* bc3 = (const float*)d_in[9];
    const float* W1 = (const float*)d_in[10];
    const float* b1 = (const float*)d_in[11];
    const float* W2 = (const float*)d_in[12];
    const float* b2 = (const float*)d_in[13];
    const float* Ws = (const float*)d_in[14];
    const float* bs = (const float*)d_in[15];
    float* out = (float*)d_out;
    float* ws = (float*)d_ws;

    hipMemsetAsync(d_ws, 0, 64 * sizeof(int), stream);   // zero barrier cells
    uber<<<NBLK, NTHR, 0, stream>>>(sf, qf, Wc0, bc0, Wc1, bc1, Wc2, bc2, Wc3, bc3,
                                    W1, b1, W2, b2, Ws, bs, out, ws);
}

// Round 9
// 233.445 us; speedup vs baseline: 2.7736x; 2.7394x over previous
//
#include <hip/hip_runtime.h>

#define CCH   640
#define RDIM  128
#define NBS   25
#define NBQ   75
#define CKK   5760
#define SF_B  64000
#define NTHR  512

// ---------------- Workspace layout (float offsets) ----------------
#define OFF_PG0 0        // [25][640] pooled(sf)
#define OFF_PGA 16000
#define OFF_PGB 32000
#define OFF_AA  48000    // [9][640] ping (k-major)
#define OFF_AB  53760    // pong
#define OFF_BBA 59520    // [16]
#define OFF_BBB 59536
#define OFF_HC  59552    // [50][128] relu'd hidden (pairs: 0-24 task, 25-49 support)
#define OFF_SKT 65952    // [2][25][900]   partials, [half][b][uv*100+p]
#define OFF_SKS 110952   // [2][9][25][100] partials, [half][uv][b][p]
#define OFF_CKS 155952   // [25][5760]
#define OFF_TKT 299952   // [9][640][100]

// K0: pool (blocks 0..31) + skS 2-way partials (blocks 32..119)
__global__ __launch_bounds__(NTHR) void k_pool_sks(
        const float* __restrict__ sf, const float* __restrict__ Ws,
        const float* __restrict__ bs, float* __restrict__ PG0, float* __restrict__ SKS) {
    int blk = blockIdx.x, t = threadIdx.x;
    if (blk < 32) {
        int idx = blk * NTHR + t;
        if (idx < NBS * CCH) {
            int b = idx / CCH, c = idx % CCH;
            const float4* s4 = (const float4*)(sf + b * SF_B + c * 100);
            float acc = 0.f;
#pragma unroll
            for (int q = 0; q < 25; ++q) {
                float4 v = s4[q];
                acc += (v.x + v.y) + (v.z + v.w);
            }
            PG0[idx] = acc * 0.01f;
        }
    } else {
        int idx = (blk - 32) * NTHR + t;
        if (idx < 2 * NBS * 900) {
            int half = idx / 22500;
            int rem = idx % 22500;
            int b = rem / 900, r2 = rem % 900;    // flat f = k*100+q
            int k = r2 / 100, q = r2 % 100;
            const float* x = sf + b * SF_B + q;
            const float* wsr = Ws + k * CCH;
            int c0 = half * 320;
            float acc = (half == 0) ? bs[k] : 0.f;
#pragma unroll 8
            for (int c = c0; c < c0 + 320; ++c)
                acc += wsr[c] * x[c * 100];
            int p = r2 / 9, uv = r2 % 9;
            SKS[half * 22500 + uv * 2500 + b * 100 + p] = acc;
        }
    }
}

// K1..K4: one chain step. Blocks <90: A'[k,c]; [90,99): beta'; [99,256): P'.
__global__ __launch_bounds__(NTHR) void k_chain(
        const float* __restrict__ Pin, const float* __restrict__ Wp,
        const float* __restrict__ bp, float* __restrict__ Pout,
        const float* __restrict__ Ain, const float* __restrict__ Wa,
        const float* __restrict__ ba, const float* __restrict__ Bin,
        float* __restrict__ Aout, float* __restrict__ Bout) {
    __shared__ float red[NTHR];
    int blk = blockIdx.x, t = threadIdx.x;
    int wv = t >> 6, lane = t & 63;
    if (blk < 90) {
        int k = blk / 10, ctile = blk % 10;
        int c = ctile * 64 + lane;
        const float* arow = Ain + k * CCH;
        int o0 = wv * 80;
        float acc = 0.f;
#pragma unroll 8
        for (int o = o0; o < o0 + 80; ++o)
            acc += arow[o] * Wa[o * CCH + c];
        red[t] = acc;
        __syncthreads();
        if (t < 64) {
            float sa = 0.f;
#pragma unroll
            for (int g = 0; g < 8; ++g) sa += red[g * 64 + t];
            Aout[k * CCH + ctile * 64 + t] = sa;
        }
    } else if (blk < 99) {
        int k = blk - 90;
        const float* arow = Ain + k * CCH;
        float v = arow[t] * ba[t];
        if (t < CCH - NTHR) v += arow[t + NTHR] * ba[t + NTHR];
        red[t] = v;
        __syncthreads();
        if (t < 64) {
            float sa = 0.f;
#pragma unroll
            for (int g = 0; g < 8; ++g) sa += red[g * 64 + t];
#pragma unroll
            for (int m = 32; m >= 1; m >>= 1) sa += __shfl_xor(sa, m);
            if (t == 0) Bout[k] = sa + Bin[k];
        }
    } else {
        int gw = (blk - 99) * 8 + wv;          // 0..1255
        for (int job = gw; job < NBS * CCH; job += 157 * 8) {
            int o = job / NBS, b = job % NBS;
            const float* wrow = Wp + o * CCH;
            const float* prow = Pin + b * CCH;
            float acc = 0.f;
#pragma unroll
            for (int s5 = 0; s5 < 10; ++s5)
                acc += wrow[s5 * 64 + lane] * prow[s5 * 64 + lane];
#pragma unroll
            for (int m = 32; m >= 1; m >>= 1) acc += __shfl_xor(acc, m);
            if (lane == 0) Pout[b * CCH + o] = acc + bp[o];
        }
    }
}

// K5: mlp1 both branches (blocks 0..49) + skT 2-way partials (blocks 50..137)
__global__ __launch_bounds__(NTHR) void k_mlp1_skt(
        const float* __restrict__ sf, const float* __restrict__ PG0,
        const float* __restrict__ PGB, const float* __restrict__ W1,
        const float* __restrict__ b1, const float* __restrict__ AB,
        const float* __restrict__ BBB, float* __restrict__ HC,
        float* __restrict__ SKT) {
    __shared__ float red[NTHR];
    int blk = blockIdx.x, t = threadIdx.x;
    if (blk < 50) {
        int pair = blk;
        int b = pair % NBS;
        const float* prow = (pair < NBS ? PGB : PG0) + b * CCH;
        int og = t >> 7, r = t & 127;
        int c0 = og * 160;
        float acc = 0.f;
#pragma unroll 8
        for (int c = c0; c < c0 + 160; ++c)
            acc += prow[c] * W1[c * RDIM + r];
        red[t] = acc;
        __syncthreads();
        if (t < RDIM) {
            float h = b1[t] + red[t] + red[RDIM + t] + red[2 * RDIM + t] + red[3 * RDIM + t];
            HC[pair * RDIM + t] = fmaxf(h, 0.f);
        }
    } else {
        int idx = (blk - 50) * NTHR + t;
        if (idx < 2 * NBS * 900) {
            int half = idx / 22500;
            int rem = idx % 22500;
            int b = rem / 900, r2 = rem % 900;
            int k = r2 / 100, q = r2 % 100;
            const float* x = sf + b * SF_B + q;
            const float* a4r = AB + k * CCH;
            int c0 = half * 320;
            float acc = (half == 0) ? BBB[k] : 0.f;
#pragma unroll 8
            for (int c = c0; c < c0 + 320; ++c)
                acc += a4r[c] * x[c * 100];
            int p = r2 / 9, uv = r2 % 9;
            SKT[half * 22500 + b * 900 + uv * 100 + p] = acc;
        }
    }
}

// K6: fused task (blocks 0..1439: computes its 4 CKT columns from h_t on the fly)
//     + CKS = h_s @ W2 + b2 (blocks 1440..1721, grid-direct)
__global__ __launch_bounds__(NTHR) void k_task_cks(
        const float* __restrict__ HC, const float* __restrict__ W2,
        const float* __restrict__ b2, const float* __restrict__ SKT,
        float* __restrict__ TKT, float* __restrict__ CKS) {
    int blk = blockIdx.x, t = threadIdx.x;
    if (blk < 1440) {
        __shared__ float ht[25 * RDIM];
        __shared__ float w2c[4 * RDIM];
        __shared__ float ck[4 * 25];
        int uv = blk / 160, cg = blk % 160;
        int c0 = cg * 4;
        for (int i = t; i < 25 * RDIM; i += NTHR) ht[i] = HC[i];   // task-branch pairs 0..24
        {
            int ci = t >> 7, r = t & 127;
            w2c[ci * RDIM + r] = W2[r * CKK + (c0 + ci) * 9 + uv];
        }
        __syncthreads();
        if (t < 100) {
            int ci = t / 25, b = t % 25;
            const float* h = ht + b * RDIM;
            const float* w = w2c + ci * RDIM;
            float acc = b2[(c0 + ci) * 9 + uv];
#pragma unroll 8
            for (int r = 0; r < RDIM; ++r) acc += h[r] * w[r];
            ck[ci * 25 + b] = acc;
        }
        __syncthreads();
        if (t < 400) {
            int ci = t / 100, p = t % 100;
            float acc = 0.f;
#pragma unroll
            for (int b = 0; b < NBS; ++b)
                acc += ck[ci * 25 + b] *
                       (SKT[b * 900 + uv * 100 + p] + SKT[22500 + b * 900 + uv * 100 + p]);
            TKT[uv * 64000 + (c0 + ci) * 100 + p] = acc * 0.04f;
        }
    } else {
        int job = (blk - 1440) * NTHR + t;
        if (job < NBS * CKK) {
            int b = job / CKK, j = job % CKK;
            const float* h = HC + (NBS + b) * RDIM;   // support-branch pairs 25..49
            float acc = b2[j];
#pragma unroll 8
            for (int r = 0; r < RDIM; ++r)
                acc += h[r] * W2[r * CKK + j];
            CKS[b * CKK + j] = acc;
        }
    }
}

// K7: merged involutions (R8/R5-verified body), direct index
__global__ __launch_bounds__(NTHR) void k_invol(
        const float* __restrict__ sf, const float* __restrict__ qf,
        const float* __restrict__ TKT, const float* __restrict__ CKS,
        const float* __restrict__ SKS, float* __restrict__ out) {
    int oidx = blockIdx.x * NTHR + threadIdx.x;      // exactly 6.4M
    bool support = oidx < NBS * SF_B;
    int b, c, p;
    const float* x;
    if (support) {
        b = oidx / SF_B; int rem = oidx % SF_B; c = rem / 100; p = rem % 100;
        x = sf + b * SF_B + c * 100;
    } else {
        int qi = oidx - NBS * SF_B;
        b = qi / SF_B; int rem = qi % SF_B; c = rem / 100; p = rem % 100;
        x = qf + b * SF_B + c * 100;
    }
    int i = p / 10, j = p % 10;
    float acc = 0.f;
#pragma unroll
    for (int u = 0; u < 3; ++u) {
        int ii = i + u - 1;
        float mrow = ((unsigned)ii < 10u) ? 1.f : 0.f;
        int ci = min(max(ii, 0), 9);
#pragma unroll
        for (int v = 0; v < 3; ++v) {
            int jj = j + v - 1;
            float m = ((unsigned)jj < 10u) ? mrow : 0.f;
            int cj = min(max(jj, 0), 9);
            float xv = x[ci * 10 + cj] * m;
            int uv = u * 3 + v;
            float w = TKT[uv * 64000 + c * 100 + p];
            if (support)
                w *= CKS[b * CKK + c * 9 + uv] *
                     (SKS[uv * 2500 + b * 100 + p] + SKS[22500 + uv * 2500 + b * 100 + p]);
            acc += w * xv;
        }
    }
    out[oidx] = acc;
}

extern "C" void kernel_launch(void* const* d_in, const int* in_sizes, int n_in,
                              void* d_out, int out_size, void* d_ws, size_t ws_size,
                              hipStream_t stream) {
    const float* sf  = (const float*)d_in[0];
    const float* qf  = (const float*)d_in[1];
    const float* Wc0 = (const float*)d_in[2];
    const float* bc0 = (const float*)d_in[3];
    const float* Wc1 = (const float*)d_in[4];
    const float* bc1 = (const float*)d_in[5];
    const float* Wc2 = (const float*)d_in[6];
    const float* bc2 = (const float*)d_in[7];
    const float* Wc3 = (const float*)d_in[8];
    const float* bc3 = (const float*)d_in[9];
    const float* W1 = (const float*)d_in[10];
    const float* b1 = (const float*)d_in[11];
    const float* W2 = (const float*)d_in[12];
    const float* b2 = (const float*)d_in[13];
    const float* Ws = (const float*)d_in[14];
    const float* bs = (const float*)d_in[15];
    float* out = (float*)d_out;
    float* ws = (float*)d_ws;

    float* PG0 = ws + OFF_PG0;
    float* PGA = ws + OFF_PGA;
    float* PGB = ws + OFF_PGB;
    float* AA  = ws + OFF_AA;
    float* AB  = ws + OFF_AB;
    float* BBA = ws + OFF_BBA;
    float* BBB = ws + OFF_BBB;
    float* HC  = ws + OFF_HC;
    float* SKT = ws + OFF_SKT;
    float* SKS = ws + OFF_SKS;
    float* CKS = ws + OFF_CKS;
    float* TKT = ws + OFF_TKT;

    // K0: pool + instance-sk partials
    k_pool_sks<<<120, NTHR, 0, stream>>>(sf, Ws, bs, PG0, SKS);
    // K1..K4: chain steps. A composes Ws·Wc4·Wc3·Wc2·Wc1; P applies Wc1..Wc4.
    k_chain<<<256, NTHR, 0, stream>>>(PG0, Wc0, bc0, PGA, Ws,  Wc3, bc3, bs,  AA, BBA);
    k_chain<<<256, NTHR, 0, stream>>>(PGA, Wc1, bc1, PGB, AA,  Wc2, bc2, BBA, AB, BBB);
    k_chain<<<256, NTHR, 0, stream>>>(PGB, Wc2, bc2, PGA, AB,  Wc1, bc1, BBB, AA, BBA);
    k_chain<<<256, NTHR, 0, stream>>>(PGA, Wc3, bc3, PGB, AA,  Wc0, bc0, BBA, AB, BBB);
    // final pooled_task = PGB, A4 = AB, beta4 = BBB
    // K5: hidden vectors + task-sk partials
    k_mlp1_skt<<<138, NTHR, 0, stream>>>(sf, PG0, PGB, W1, b1, AB, BBB, HC, SKT);
    // K6: fused task kernel + support ck
    k_task_cks<<<1722, NTHR, 0, stream>>>(HC, W2, b2, SKT, TKT, CKS);
    // K7: involutions
    k_invol<<<12500, NTHR, 0, stream>>>(sf, qf, TKT, CKS, SKS, out);
}